// Round 7
// baseline (555.381 us; speedup 1.0000x reference)
//
#include <hip/hip_runtime.h>

typedef __attribute__((ext_vector_type(8))) short bf16x8;
typedef __attribute__((ext_vector_type(4))) float f32x4;
typedef __attribute__((ext_vector_type(4))) unsigned short us4;
typedef __attribute__((ext_vector_type(8))) unsigned short us8;

#define NROWS 262144
#define KC 256
#define DD 256
#define BM 64        // rows per block
#define DK 32        // D-chunk (= one MFMA K)
#define SW 40        // LDS k-stride in bf16 (80B rows, 16B-aligned)
#define TAU 1e-3f    // flag threshold: covers 2-pass MFMA err (sigma~7e-5, 12sigma) + np fp32 rounding
#define FCAP 32768   // flag list capacity

// ===== bit-exact numpy emulation helpers (defeat -ffp-contract) =====
__device__ __forceinline__ float np_pw128_sq(const float* a) {
    float r[8];
#pragma unroll
    for (int j = 0; j < 8; ++j) r[j] = __fmul_rn(a[j], a[j]);
    for (int i = 8; i < 128; i += 8) {
#pragma unroll
        for (int j = 0; j < 8; ++j)
            r[j] = __fadd_rn(r[j], __fmul_rn(a[i + j], a[i + j]));
    }
    float t01 = __fadd_rn(r[0], r[1]), t23 = __fadd_rn(r[2], r[3]);
    float t45 = __fadd_rn(r[4], r[5]), t67 = __fadd_rn(r[6], r[7]);
    return __fadd_rn(__fadd_rn(t01, t23), __fadd_rn(t45, t67));
}
__device__ __forceinline__ float np_sum256_sq(const float* a) {
    return __fadd_rn(np_pw128_sq(a), np_pw128_sq(a + 128));
}

// split fp32 x = hi + lo (bf16 each): hi = truncate, lo = RNE(x - hi); returns (hi<<16)|lo
__device__ __forceinline__ unsigned cvt_split(float x) {
    unsigned b = __float_as_uint(x);
    unsigned hi = b >> 16;
    float hif = __uint_as_float(b & 0xFFFF0000u);
    float r = x - hif;
    unsigned rb = __float_as_uint(r);
    rb += 0x7FFFu + ((rb >> 16) & 1u);
    return (hi << 16) | (rb >> 16);
}

// ---------- prep: se[k] = np-bit-exact sum(emb[k]^2); zero accum + flag count ----------
__global__ void vq_prep(const float* __restrict__ emb, float* __restrict__ se,
                        double* __restrict__ accum, int* __restrict__ gcnt) {
    int k = threadIdx.x;
    if (k == 0) { *accum = 0.0; *gcnt = 0; }
    se[k] = np_sum256_sq(emb + (size_t)k * DD);
}

// ---------- split emb -> dc-tiled bf16 hi/lo planes: plane[tile][k][32] ----------
__global__ void vq_split(const float* __restrict__ emb,
                         unsigned short* __restrict__ ph,
                         unsigned short* __restrict__ pl) {
    int f = (blockIdx.x * 256 + threadIdx.x) * 4;   // element index
    float4 v = *reinterpret_cast<const float4*>(emb + f);
    int k = f >> 8, d = f & 255;
    int off = (d >> 5) * (KC * DK) + k * DK + (d & 31);
    unsigned p0 = cvt_split(v.x), p1 = cvt_split(v.y);
    unsigned p2 = cvt_split(v.z), p3 = cvt_split(v.w);
    us4 h, l;
    h[0] = (unsigned short)(p0 >> 16); l[0] = (unsigned short)p0;
    h[1] = (unsigned short)(p1 >> 16); l[1] = (unsigned short)p1;
    h[2] = (unsigned short)(p2 >> 16); l[2] = (unsigned short)p2;
    h[3] = (unsigned short)(p3 >> 16); l[3] = (unsigned short)p3;
    *reinterpret_cast<us4*>(ph + off) = h;
    *reinterpret_cast<us4*>(pl + off) = l;
}

// ---------- main: per-block 64 rows x 256 codes, 2-pass bf16-split MFMA ----------
__global__ __launch_bounds__(256, 3)
void vq_main(const float* __restrict__ ze, const float* __restrict__ emb,
             const unsigned short* __restrict__ ph, const unsigned short* __restrict__ pl,
             const float* __restrict__ se_g, float* __restrict__ out_zq,
             float* __restrict__ out_inds, double* __restrict__ accum,
             int* __restrict__ glist, int* __restrict__ gcnt)
{
    __shared__ __attribute__((aligned(16))) unsigned short zs_hi[BM * SW];
    __shared__ __attribute__((aligned(16))) unsigned short es_hi[KC * SW];  // epilogue: wv1/wv2/wk1
    __shared__ __attribute__((aligned(16))) unsigned short es_lo[KC * SW];  // epilogue: red
    __shared__ float  se_s[KC];
    __shared__ int    inds_s[BM];

    // epilogue aliases (es dead after post-loop barrier)
    float* wv1 = reinterpret_cast<float*>(es_hi);            // [4*BM]
    float* wv2 = wv1 + 4 * BM;                               // [4*BM]
    int*   wk1 = reinterpret_cast<int*>(wv2 + 4 * BM);       // [4*BM]
    float* red = reinterpret_cast<float*>(es_lo);            // [256]

    const int t = threadIdx.x;
    const int w = t >> 6;          // wave: cols [64w, 64w+64)
    const int l = t & 63;
    const int q = (t >> 4) & 3;    // lane quad
    const int c = t & 15;
    const size_t m0 = (size_t)blockIdx.x * BM;
    const float* zbase = ze + m0 * DD;

    se_s[t] = se_g[t];

    f32x4 acc[4][4];
#pragma unroll
    for (int i = 0; i < 4; ++i)
#pragma unroll
        for (int j = 0; j < 4; ++j) acc[i][j] = (f32x4){0.f, 0.f, 0.f, 0.f};
    float sz_acc = 0.f;

    // z-stage mapping: idx in [0,512): row = idx>>3, c4 = idx&7 (two idx per thread)
    const int i0 = t, i1 = 256 + t;
    const int r0 = i0 >> 3, c40 = i0 & 7;
    const int r1 = i1 >> 3, c41 = i1 & 7;

    // prologue: prefetch z tile for dc=0
    float4 zva = *reinterpret_cast<const float4*>(zbase + (size_t)r0 * DD + 0 + c40 * 4);
    float4 zvb = *reinterpret_cast<const float4*>(zbase + (size_t)r1 * DD + 0 + c41 * 4);

    for (int dci = 0; dci < 8; ++dci) {
        const int dc = dci * DK;
        __syncthreads();
        // ---- stage e tile: pure copy from pre-split tiled planes (L2-hot) ----
        const unsigned short* ehp = ph + (dc >> 5) * (KC * DK);
        const unsigned short* elp = pl + (dc >> 5) * (KC * DK);
#pragma unroll
        for (int it = 0; it < 4; ++it) {
            int idx = it * 256 + t;
            int row = idx >> 2, c8 = idx & 3;
            us8 h  = *reinterpret_cast<const us8*>(ehp + idx * 8);
            us8 lo = *reinterpret_cast<const us8*>(elp + idx * 8);
            *reinterpret_cast<us8*>(&es_hi[row * SW + c8 * 8]) = h;
            *reinterpret_cast<us8*>(&es_lo[row * SW + c8 * 8]) = lo;
        }
        // ---- write prefetched z regs -> LDS (truncation only, no lo plane) ----
        {
            sz_acc = fmaf(zva.x, zva.x, sz_acc); sz_acc = fmaf(zva.y, zva.y, sz_acc);
            sz_acc = fmaf(zva.z, zva.z, sz_acc); sz_acc = fmaf(zva.w, zva.w, sz_acc);
            us4 h;
            h[0] = (unsigned short)(__float_as_uint(zva.x) >> 16);
            h[1] = (unsigned short)(__float_as_uint(zva.y) >> 16);
            h[2] = (unsigned short)(__float_as_uint(zva.z) >> 16);
            h[3] = (unsigned short)(__float_as_uint(zva.w) >> 16);
            *reinterpret_cast<us4*>(&zs_hi[r0 * SW + c40 * 4]) = h;
        }
        {
            sz_acc = fmaf(zvb.x, zvb.x, sz_acc); sz_acc = fmaf(zvb.y, zvb.y, sz_acc);
            sz_acc = fmaf(zvb.z, zvb.z, sz_acc); sz_acc = fmaf(zvb.w, zvb.w, sz_acc);
            us4 h;
            h[0] = (unsigned short)(__float_as_uint(zvb.x) >> 16);
            h[1] = (unsigned short)(__float_as_uint(zvb.y) >> 16);
            h[2] = (unsigned short)(__float_as_uint(zvb.z) >> 16);
            h[3] = (unsigned short)(__float_as_uint(zvb.w) >> 16);
            *reinterpret_cast<us4*>(&zs_hi[r1 * SW + c41 * 4]) = h;
        }
        // ---- issue prefetch for next dc (completes under MFMA phase) ----
        if (dci < 7) {
            zva = *reinterpret_cast<const float4*>(zbase + (size_t)r0 * DD + dc + DK + c40 * 4);
            zvb = *reinterpret_cast<const float4*>(zbase + (size_t)r1 * DD + dc + DK + c41 * 4);
        }
        __syncthreads();
        // ---- MFMA: wave tile 64 rows x 64 cols, 4x4 frags, 2 passes ----
        bf16x8 a_hi[4], b_hi[4], b_lo[4];
#pragma unroll
        for (int mf = 0; mf < 4; ++mf)
            a_hi[mf] = *reinterpret_cast<const bf16x8*>(&zs_hi[(16 * mf + c) * SW + q * 8]);
#pragma unroll
        for (int nf = 0; nf < 4; ++nf) {
            b_hi[nf] = *reinterpret_cast<const bf16x8*>(&es_hi[(64 * w + 16 * nf + c) * SW + q * 8]);
            b_lo[nf] = *reinterpret_cast<const bf16x8*>(&es_lo[(64 * w + 16 * nf + c) * SW + q * 8]);
        }
#pragma unroll
        for (int mf = 0; mf < 4; ++mf)
#pragma unroll
            for (int nf = 0; nf < 4; ++nf) {
                acc[mf][nf] = __builtin_amdgcn_mfma_f32_16x16x32_bf16(a_hi[mf], b_lo[nf], acc[mf][nf], 0, 0, 0);
                acc[mf][nf] = __builtin_amdgcn_mfma_f32_16x16x32_bf16(a_hi[mf], b_hi[nf], acc[mf][nf], 0, 0, 0);
            }
    }
    __syncthreads();   // es region now dead -> safe for epilogue aliases

    // ---- per-row argmin over this wave's 64-col slice (v1, v2, k1) ----
#pragma unroll
    for (int mf = 0; mf < 4; ++mf)
#pragma unroll
        for (int j = 0; j < 4; ++j) {
            float v1 = 3.4e38f, v2 = 3.4e38f; int k1 = 0x7fffffff;
#pragma unroll
            for (int nf = 0; nf < 4; ++nf) {
                int k = 64 * w + 16 * nf + c;
                float dv = fmaf(-2.f, acc[mf][nf][j], se_s[k]);
                if (dv < v1) { v2 = v1; v1 = dv; k1 = k; }
                else if (dv < v2) { v2 = dv; }
            }
#pragma unroll
            for (int off = 1; off < 16; off <<= 1) {
                float ov1 = __shfl_xor(v1, off, 64);
                float ov2 = __shfl_xor(v2, off, 64);
                int   ok1 = __shfl_xor(k1, off, 64);
                bool other = (ov1 < v1) || (ov1 == v1 && ok1 < k1);
                float nv2 = other ? fminf(v1, ov2) : fminf(v2, ov1);
                if (other) { v1 = ov1; k1 = ok1; }
                v2 = nv2;
            }
            if (c == 0) {
                int row = 16 * mf + 4 * q + j;
                wv1[w * BM + row] = v1; wv2[w * BM + row] = v2; wk1[w * BM + row] = k1;
            }
        }
    __syncthreads();

    // ---- cross-wave merge (t < 64: one row each), flag near-ties to GLOBAL list ----
    float lossv = 0.f;
    if (t < BM) {
        float v1 = wv1[t], v2 = wv2[t]; int k1 = wk1[t];
#pragma unroll
        for (int ww = 1; ww < 4; ++ww) {
            float ov1 = wv1[ww * BM + t], ov2 = wv2[ww * BM + t];
            int ok1 = wk1[ww * BM + t];
            bool other = (ov1 < v1) || (ov1 == v1 && ok1 < k1);
            float nv2 = other ? fminf(v1, ov2) : fminf(v2, ov1);
            if (other) { v1 = ov1; k1 = ok1; }
            v2 = nv2;
        }
        inds_s[t] = k1;
        lossv = v1;
        if (v2 - v1 < TAU) {
            int s = atomicAdd(gcnt, 1);
            if (s < FCAP) glist[s] = (int)(m0 + t);
        }
    }
    __syncthreads();

    // ---- write indices (as float) ----
    if (t < BM) out_inds[m0 + t] = (float)inds_s[t];

    // ---- gather + write z_q (wave per row, lane per float4) ----
    for (int r = w; r < BM; r += 4) {
        int k = inds_s[r];
        float4 v = *reinterpret_cast<const float4*>(emb + (size_t)k * DD + l * 4);
        *reinterpret_cast<float4*>(out_zq + (m0 + r) * DD + l * 4) = v;
    }

    // ---- loss partial ----
    red[t] = sz_acc + lossv;
    __syncthreads();
    for (int s = 128; s > 0; s >>= 1) {
        if (t < s) red[t] += red[t + s];
        __syncthreads();
    }
    if (t == 0) atomicAdd(accum, (double)red[0]);
}

// ---------- deferred fix: BIT-EXACT numpy fp32 pipeline for flagged rows (r3-proven) ----------
__global__ __launch_bounds__(256)
void vq_fix(const float* __restrict__ ze, const float* __restrict__ emb,
            const float* __restrict__ se_g, const int* __restrict__ glist,
            const int* __restrict__ gcnt, float* __restrict__ out_zq,
            float* __restrict__ out_inds)
{
    __shared__ float zf[256];
    __shared__ float srow;
    __shared__ float red[256];
    __shared__ int   rk[256];

    const int t = threadIdx.x;
    int F = *gcnt; if (F > FCAP) F = FCAP;
    const float se_k = se_g[t];
    const float4* e4p = reinterpret_cast<const float4*>(emb + (size_t)t * DD);

    for (int i = blockIdx.x; i < F; i += gridDim.x) {
        int row = glist[i];
        __syncthreads();   // protect zf reuse across iterations
        if (t < 64)
            reinterpret_cast<float4*>(zf)[t] =
                reinterpret_cast<const float4*>(ze + (size_t)row * DD)[t];
        __syncthreads();
        if (t == 0) srow = np_sum256_sq(zf);
        __syncthreads();
        // thread t emulates code k=t: sequential single-accumulator FMA over d
        float m32 = 0.f;
        for (int d4 = 0; d4 < 64; ++d4) {
            float4 e4 = e4p[d4];
            int d = d4 * 4;
            m32 = __fmaf_rn(zf[d + 0], e4.x, m32);
            m32 = __fmaf_rn(zf[d + 1], e4.y, m32);
            m32 = __fmaf_rn(zf[d + 2], e4.z, m32);
            m32 = __fmaf_rn(zf[d + 3], e4.w, m32);
        }
        float A  = __fadd_rn(srow, se_k);
        float Dq = __fsub_rn(A, __fmul_rn(2.0f, m32));
        red[t] = Dq; rk[t] = t;
        __syncthreads();
        for (int s = 128; s > 0; s >>= 1) {
            if (t < s) {
                float vo = red[t + s]; int ko = rk[t + s];
                if (vo < red[t] || (vo == red[t] && ko < rk[t])) { red[t] = vo; rk[t] = ko; }
            }
            __syncthreads();
        }
        int kk = rk[0];
        if (t == 0) out_inds[row] = (float)kk;
        out_zq[(size_t)row * DD + t] = emb[(size_t)kk * DD + t];
    }
}

// ---------- finalize: loss = (1 + 0.25) * mean((z - q)^2) ----------
__global__ void vq_fin(const double* __restrict__ accum, float* __restrict__ out_loss) {
    *out_loss = (float)(1.25 * (*accum) / ((double)NROWS * (double)DD));
}

extern "C" void kernel_launch(void* const* d_in, const int* in_sizes, int n_in,
                              void* d_out, int out_size, void* d_ws, size_t ws_size,
                              hipStream_t stream) {
    const float* ze  = (const float*)d_in[0];
    const float* emb = (const float*)d_in[1];
    float* out      = (float*)d_out;
    float* out_zq   = out;
    float* out_inds = out + (size_t)NROWS * DD;
    float* out_loss = out + (size_t)NROWS * DD + NROWS;

    double* accum = (double*)d_ws;                                   // @0, 8B
    int*    gcnt  = (int*)((char*)d_ws + 8);                         // @8, 4B
    float*  se    = (float*)((char*)d_ws + 256);                     // @256, 1KB
    int*    glist = (int*)((char*)d_ws + 4096);                      // @4K, 128KB
    unsigned short* ph = (unsigned short*)((char*)d_ws + 4096 + 131072);           // 128KB
    unsigned short* pl = (unsigned short*)((char*)d_ws + 4096 + 131072 + 131072);  // 128KB

    vq_prep<<<1, 256, 0, stream>>>(emb, se, accum, gcnt);
    vq_split<<<KC * DD / (256 * 4), 256, 0, stream>>>(emb, ph, pl);
    vq_main<<<NROWS / BM, 256, 0, stream>>>(ze, emb, ph, pl, se, out_zq, out_inds,
                                            accum, glist, gcnt);
    vq_fix<<<2048, 256, 0, stream>>>(ze, emb, se, glist, gcnt, out_zq, out_inds);
    vq_fin<<<1, 1, 0, stream>>>(accum, out_loss);
}

// Round 8
// 332.325 us; speedup vs baseline: 1.6712x; 1.6712x over previous
//
#include <hip/hip_runtime.h>

typedef __attribute__((ext_vector_type(8))) short bf16x8;
typedef __attribute__((ext_vector_type(4))) float f32x4;
typedef __attribute__((ext_vector_type(4))) unsigned short us4;
typedef __attribute__((ext_vector_type(8))) unsigned short us8;

#define NROWS 262144
#define KC 256
#define DD 256
#define BM 64        // rows per block
#define DK 32        // D-chunk (= one MFMA K)
#define SW 40        // LDS k-stride in bf16 (80B rows, 16B-aligned)
#define TAU 1.5e-3f  // flag threshold: 6.6 sigma of single-pass bf16 error (1.6e-4) + np fp32 rounding
#define FCAP 65536   // flag list capacity

// ===== bit-exact numpy emulation helpers (defeat -ffp-contract) =====
__device__ __forceinline__ float np_pw128_sq(const float* a) {
    float r[8];
#pragma unroll
    for (int j = 0; j < 8; ++j) r[j] = __fmul_rn(a[j], a[j]);
    for (int i = 8; i < 128; i += 8) {
#pragma unroll
        for (int j = 0; j < 8; ++j)
            r[j] = __fadd_rn(r[j], __fmul_rn(a[i + j], a[i + j]));
    }
    float t01 = __fadd_rn(r[0], r[1]), t23 = __fadd_rn(r[2], r[3]);
    float t45 = __fadd_rn(r[4], r[5]), t67 = __fadd_rn(r[6], r[7]);
    return __fadd_rn(__fadd_rn(t01, t23), __fadd_rn(t45, t67));
}
__device__ __forceinline__ float np_sum256_sq(const float* a) {
    return __fadd_rn(np_pw128_sq(a), np_pw128_sq(a + 128));
}

// bf16 round-to-nearest-even
__device__ __forceinline__ unsigned short bf16_rne(float x) {
    unsigned b = __float_as_uint(x);
    b += 0x7FFFu + ((b >> 16) & 1u);
    return (unsigned short)(b >> 16);
}

// ---------- prep: se[k] = np-bit-exact sum(emb[k]^2); zero accum + flag count ----------
__global__ void vq_prep(const float* __restrict__ emb, float* __restrict__ se,
                        double* __restrict__ accum, int* __restrict__ gcnt) {
    int k = threadIdx.x;
    if (k == 0) { *accum = 0.0; *gcnt = 0; }
    se[k] = np_sum256_sq(emb + (size_t)k * DD);
}

// ---------- split emb -> dc-tiled bf16 (RNE) plane: plane[tile][k][32] ----------
__global__ void vq_split(const float* __restrict__ emb, unsigned short* __restrict__ ph) {
    int f = (blockIdx.x * 256 + threadIdx.x) * 4;   // element index
    float4 v = *reinterpret_cast<const float4*>(emb + f);
    int k = f >> 8, d = f & 255;
    int off = (d >> 5) * (KC * DK) + k * DK + (d & 31);
    us4 h;
    h[0] = bf16_rne(v.x); h[1] = bf16_rne(v.y);
    h[2] = bf16_rne(v.z); h[3] = bf16_rne(v.w);
    *reinterpret_cast<us4*>(ph + off) = h;
}

// ---------- main: per-block 64 rows x 256 codes, single-pass bf16 MFMA ----------
__global__ __launch_bounds__(256, 4)
void vq_main(const float* __restrict__ ze, const float* __restrict__ emb,
             const unsigned short* __restrict__ ph,
             const float* __restrict__ se_g, float* __restrict__ out_zq,
             float* __restrict__ out_inds, double* __restrict__ accum,
             int* __restrict__ glist, int* __restrict__ gcnt)
{
    __shared__ __attribute__((aligned(16))) unsigned short zs_hi[BM * SW];   // epilogue: red
    __shared__ __attribute__((aligned(16))) unsigned short es_hi[KC * SW];   // epilogue: wv1/wv2/wk1
    __shared__ float  se_s[KC];
    __shared__ int    inds_s[BM];

    // epilogue aliases (regions dead after post-loop barrier)
    float* wv1 = reinterpret_cast<float*>(es_hi);            // [4*BM]
    float* wv2 = wv1 + 4 * BM;                               // [4*BM]
    int*   wk1 = reinterpret_cast<int*>(wv2 + 4 * BM);       // [4*BM]
    float* red = reinterpret_cast<float*>(zs_hi);            // [256]

    const int t = threadIdx.x;
    const int w = t >> 6;          // wave: cols [64w, 64w+64)
    const int l = t & 63;
    const int q = (t >> 4) & 3;    // lane quad
    const int c = t & 15;
    const size_t m0 = (size_t)blockIdx.x * BM;
    const float* zbase = ze + m0 * DD;

    se_s[t] = se_g[t];

    f32x4 acc[4][4];
#pragma unroll
    for (int i = 0; i < 4; ++i)
#pragma unroll
        for (int j = 0; j < 4; ++j) acc[i][j] = (f32x4){0.f, 0.f, 0.f, 0.f};
    float sz_acc = 0.f;

    // z-stage mapping: idx in [0,512): row = idx>>3, c4 = idx&7 (two idx per thread)
    const int r0 = t >> 3, c40 = t & 7;
    const int r1 = (256 + t) >> 3, c41 = t & 7;

    // prologue: prefetch z tile for dc=0
    float4 zva = *reinterpret_cast<const float4*>(zbase + (size_t)r0 * DD + c40 * 4);
    float4 zvb = *reinterpret_cast<const float4*>(zbase + (size_t)r1 * DD + c41 * 4);

    for (int dci = 0; dci < 8; ++dci) {
        const int dc = dci * DK;
        __syncthreads();
        // ---- stage e tile: pure copy from pre-split tiled plane (L2-hot) ----
        const unsigned short* ehp = ph + dci * (KC * DK);
#pragma unroll
        for (int it = 0; it < 4; ++it) {
            int idx = it * 256 + t;
            int row = idx >> 2, c8 = idx & 3;
            us8 h = *reinterpret_cast<const us8*>(ehp + idx * 8);
            *reinterpret_cast<us8*>(&es_hi[row * SW + c8 * 8]) = h;
        }
        // ---- write prefetched z regs -> LDS (RNE bf16) ----
        {
            sz_acc = fmaf(zva.x, zva.x, sz_acc); sz_acc = fmaf(zva.y, zva.y, sz_acc);
            sz_acc = fmaf(zva.z, zva.z, sz_acc); sz_acc = fmaf(zva.w, zva.w, sz_acc);
            us4 h;
            h[0] = bf16_rne(zva.x); h[1] = bf16_rne(zva.y);
            h[2] = bf16_rne(zva.z); h[3] = bf16_rne(zva.w);
            *reinterpret_cast<us4*>(&zs_hi[r0 * SW + c40 * 4]) = h;
        }
        {
            sz_acc = fmaf(zvb.x, zvb.x, sz_acc); sz_acc = fmaf(zvb.y, zvb.y, sz_acc);
            sz_acc = fmaf(zvb.z, zvb.z, sz_acc); sz_acc = fmaf(zvb.w, zvb.w, sz_acc);
            us4 h;
            h[0] = bf16_rne(zvb.x); h[1] = bf16_rne(zvb.y);
            h[2] = bf16_rne(zvb.z); h[3] = bf16_rne(zvb.w);
            *reinterpret_cast<us4*>(&zs_hi[r1 * SW + c41 * 4]) = h;
        }
        // ---- issue prefetch for next dc (completes under MFMA phase) ----
        if (dci < 7) {
            zva = *reinterpret_cast<const float4*>(zbase + (size_t)r0 * DD + dc + DK + c40 * 4);
            zvb = *reinterpret_cast<const float4*>(zbase + (size_t)r1 * DD + dc + DK + c41 * 4);
        }
        __syncthreads();
        // ---- MFMA: wave tile 64 rows x 64 cols, 4x4 frags, single pass ----
        bf16x8 a_hi[4], b_hi[4];
#pragma unroll
        for (int mf = 0; mf < 4; ++mf)
            a_hi[mf] = *reinterpret_cast<const bf16x8*>(&zs_hi[(16 * mf + c) * SW + q * 8]);
#pragma unroll
        for (int nf = 0; nf < 4; ++nf)
            b_hi[nf] = *reinterpret_cast<const bf16x8*>(&es_hi[(64 * w + 16 * nf + c) * SW + q * 8]);
#pragma unroll
        for (int mf = 0; mf < 4; ++mf)
#pragma unroll
            for (int nf = 0; nf < 4; ++nf)
                acc[mf][nf] = __builtin_amdgcn_mfma_f32_16x16x32_bf16(a_hi[mf], b_hi[nf], acc[mf][nf], 0, 0, 0);
    }
    __syncthreads();   // zs/es regions now dead -> safe for epilogue aliases

    // ---- per-row argmin over this wave's 64-col slice (v1, v2, k1) ----
#pragma unroll
    for (int mf = 0; mf < 4; ++mf)
#pragma unroll
        for (int j = 0; j < 4; ++j) {
            float v1 = 3.4e38f, v2 = 3.4e38f; int k1 = 0x7fffffff;
#pragma unroll
            for (int nf = 0; nf < 4; ++nf) {
                int k = 64 * w + 16 * nf + c;
                float dv = fmaf(-2.f, acc[mf][nf][j], se_s[k]);
                if (dv < v1) { v2 = v1; v1 = dv; k1 = k; }
                else if (dv < v2) { v2 = dv; }
            }
#pragma unroll
            for (int off = 1; off < 16; off <<= 1) {
                float ov1 = __shfl_xor(v1, off, 64);
                float ov2 = __shfl_xor(v2, off, 64);
                int   ok1 = __shfl_xor(k1, off, 64);
                bool other = (ov1 < v1) || (ov1 == v1 && ok1 < k1);
                float nv2 = other ? fminf(v1, ov2) : fminf(v2, ov1);
                if (other) { v1 = ov1; k1 = ok1; }
                v2 = nv2;
            }
            if (c == 0) {
                int row = 16 * mf + 4 * q + j;
                wv1[w * BM + row] = v1; wv2[w * BM + row] = v2; wk1[w * BM + row] = k1;
            }
        }
    __syncthreads();

    // ---- cross-wave merge (t < 64: one row each), flag near-ties to GLOBAL list ----
    float lossv = 0.f;
    if (t < BM) {
        float v1 = wv1[t], v2 = wv2[t]; int k1 = wk1[t];
#pragma unroll
        for (int ww = 1; ww < 4; ++ww) {
            float ov1 = wv1[ww * BM + t], ov2 = wv2[ww * BM + t];
            int ok1 = wk1[ww * BM + t];
            bool other = (ov1 < v1) || (ov1 == v1 && ok1 < k1);
            float nv2 = other ? fminf(v1, ov2) : fminf(v2, ov1);
            if (other) { v1 = ov1; k1 = ok1; }
            v2 = nv2;
        }
        inds_s[t] = k1;
        lossv = v1;
        if (v2 - v1 < TAU) {
            int s = atomicAdd(gcnt, 1);
            if (s < FCAP) glist[s] = (int)(m0 + t);
        }
    }
    __syncthreads();

    // ---- write indices (as float) ----
    if (t < BM) out_inds[m0 + t] = (float)inds_s[t];

    // ---- gather + write z_q (wave per row, lane per float4) ----
    for (int r = w; r < BM; r += 4) {
        int k = inds_s[r];
        float4 v = *reinterpret_cast<const float4*>(emb + (size_t)k * DD + l * 4);
        *reinterpret_cast<float4*>(out_zq + (m0 + r) * DD + l * 4) = v;
    }

    // ---- loss partial ----
    red[t] = sz_acc + lossv;
    __syncthreads();
    for (int s = 128; s > 0; s >>= 1) {
        if (t < s) red[t] += red[t + s];
        __syncthreads();
    }
    if (t == 0) atomicAdd(accum, (double)red[0]);
}

// ---------- deferred fix: bit-exact np fp32 pipeline, BATCHED 16 rows/group ----------
// emb streamed ONCE per 16 rows (16x less L2 traffic than r7). Arithmetic identical to r3.
__global__ __launch_bounds__(256)
void vq_fix(const float* __restrict__ ze, const float* __restrict__ emb,
            const float* __restrict__ se_g, const int* __restrict__ glist,
            const int* __restrict__ gcnt, float* __restrict__ out_zq,
            float* __restrict__ out_inds)
{
    __shared__ float dq[16][256];
    __shared__ float srow_s[16];
    __shared__ int   rowid_s[16];
    __shared__ int   klds[16];

    const int t = threadIdx.x;
    int F = *gcnt; if (F > FCAP) F = FCAP;
    const float se_k = se_g[t];
    const float4* e4p = reinterpret_cast<const float4*>(emb + (size_t)t * DD);

    for (int g = blockIdx.x * 16; g < F; g += gridDim.x * 16) {
        __syncthreads();   // protect LDS reuse across iterations
        if (t < 16) {
            int idx = g + t; if (idx > F - 1) idx = F - 1;   // pad tail with dup of last
            int row = glist[idx];
            rowid_s[t] = row;
            srow_s[t] = np_sum256_sq(ze + (size_t)row * DD);
        }
        __syncthreads();

        // wave-uniform z-row pointers (scalar loads)
        const float* zp[16];
#pragma unroll
        for (int r = 0; r < 16; ++r)
            zp[r] = ze + (size_t)__builtin_amdgcn_readfirstlane(rowid_s[r]) * DD;

        // thread t emulates code k=t for all 16 rows: sequential 1-acc FMA over d
        float m32[16];
#pragma unroll
        for (int r = 0; r < 16; ++r) m32[r] = 0.f;
        for (int d4 = 0; d4 < 64; ++d4) {
            float4 e4 = e4p[d4];
            const int d = d4 * 4;
#pragma unroll
            for (int r = 0; r < 16; ++r) {
                m32[r] = __fmaf_rn(zp[r][d + 0], e4.x, m32[r]);
                m32[r] = __fmaf_rn(zp[r][d + 1], e4.y, m32[r]);
                m32[r] = __fmaf_rn(zp[r][d + 2], e4.z, m32[r]);
                m32[r] = __fmaf_rn(zp[r][d + 3], e4.w, m32[r]);
            }
        }
#pragma unroll
        for (int r = 0; r < 16; ++r) {
            float A = __fadd_rn(srow_s[r], se_k);
            dq[r][t] = __fsub_rn(A, __fmul_rn(2.0f, m32[r]));
        }
        __syncthreads();

        // per-row argmin: 16 threads per row (r = t>>4, portion p = t&15)
        {
            const int r = t >> 4, p = t & 15;
            float bv = 3.4e38f; int bk = 0x7fffffff;
#pragma unroll
            for (int i = 0; i < 16; ++i) {
                int k = p * 16 + i;
                float v = dq[r][k];
                if (v < bv) { bv = v; bk = k; }   // strict <: lowest index in subset
            }
#pragma unroll
            for (int off = 1; off < 16; off <<= 1) {
                float ov = __shfl_xor(bv, off, 64);
                int   ok = __shfl_xor(bk, off, 64);
                if (ov < bv || (ov == bv && ok < bk)) { bv = ov; bk = ok; }
            }
            if (p == 0) klds[r] = bk;
        }
        __syncthreads();

        int R = F - g; if (R > 16) R = 16;
#pragma unroll
        for (int r = 0; r < 16; ++r) {
            if (r < R) {
                int row = rowid_s[r];
                int kk  = klds[r];
                out_zq[(size_t)row * DD + t] = emb[(size_t)kk * DD + t];
                if (t == 0) out_inds[row] = (float)kk;
            }
        }
    }
}

// ---------- finalize: loss = (1 + 0.25) * mean((z - q)^2) ----------
__global__ void vq_fin(const double* __restrict__ accum, float* __restrict__ out_loss) {
    *out_loss = (float)(1.25 * (*accum) / ((double)NROWS * (double)DD));
}

extern "C" void kernel_launch(void* const* d_in, const int* in_sizes, int n_in,
                              void* d_out, int out_size, void* d_ws, size_t ws_size,
                              hipStream_t stream) {
    const float* ze  = (const float*)d_in[0];
    const float* emb = (const float*)d_in[1];
    float* out      = (float*)d_out;
    float* out_zq   = out;
    float* out_inds = out + (size_t)NROWS * DD;
    float* out_loss = out + (size_t)NROWS * DD + NROWS;

    double* accum = (double*)d_ws;                                   // @0, 8B
    int*    gcnt  = (int*)((char*)d_ws + 8);                         // @8, 4B
    float*  se    = (float*)((char*)d_ws + 256);                     // @256, 1KB
    int*    glist = (int*)((char*)d_ws + 4096);                      // @4K, 256KB
    unsigned short* ph = (unsigned short*)((char*)d_ws + 4096 + 262144);  // 128KB

    vq_prep<<<1, 256, 0, stream>>>(emb, se, accum, gcnt);
    vq_split<<<KC * DD / (256 * 4), 256, 0, stream>>>(emb, ph);
    vq_main<<<NROWS / BM, 256, 0, stream>>>(ze, emb, ph, se, out_zq, out_inds,
                                            accum, glist, gcnt);
    vq_fix<<<1024, 256, 0, stream>>>(ze, emb, se, glist, gcnt, out_zq, out_inds);
    vq_fin<<<1, 1, 0, stream>>>(accum, out_loss);
}